// Round 3
// baseline (8087.799 us; speedup 1.0000x reference)
//
#include <hip/hip_runtime.h>
#include <cstdint>
#include <cstddef>

// ============================================================================
// Actor rollout, round 3: 2 kernels/step (was 5).
//  - gru_fused: GRU GEMMs + gates + limb-split in one kernel; h stored
//    TRANSPOSED (hT[k][b]) so the skinny GEMM reads h coalesced from L2
//    with no LDS staging; wave-uniform weight rows -> scalar loads.
//  - logits_mfma: split-bf16 MFMA GEMM + per-strip softmax/Gumbel partials +
//    in-kernel final combine via device-scope ticket (last 8 blocks reduce
//    8 rows each). Writes raw z to dist; rmax/lse stored per (t,b).
//  - norm_all_k once at the end: normalizes all dist, computes probs.
// PRNG: JAX threefry2x32 partitionable variant (bit-exact).
// ============================================================================

#define JAX_PARTITIONABLE 1

#define Bn 64
#define Tn 64
#define Vn 32000
#define Hn 512
#define En 256

#define NSTRIP 500   // logits blocks (Vn/64)
#define SPAD   512   // padded strip stride

typedef unsigned short u16;
typedef __attribute__((ext_vector_type(8))) __bf16 bf16x8;
typedef __attribute__((ext_vector_type(4))) float f32x4;
typedef __attribute__((ext_vector_type(4))) uint32_t u32x4;

// ---------------- output layout (floats) ----------------
#define OUT_SAMP 0                      // (B,T)
#define OUT_CORR (Bn * Tn)              // (B,T)
#define OUT_LOGP (2 * Bn * Tn)          // (B,T)
#define OUT_DIST (3 * Bn * Tn)          // (B,T,V) at [((b*T)+t)*V + v]
#define OUT_PROB (3 * Bn * Tn + (size_t)Bn * Tn * Vn)  // (T,V)

// ---------------- ws layout (float offsets) ----------------
#define WS_HT0  0                        // Hn*Bn  (hT[k][b])
#define WS_HT1  (WS_HT0 + Hn * Bn)
#define WS_RM   (WS_HT1 + Hn * Bn)       // Tn*Bn rowmax
#define WS_RL   (WS_RM + Tn * Bn)        // Tn*Bn rowlse
#define WS_SMP  (WS_RL + Tn * Bn)        // Bn int
#define WS_CNT  (WS_SMP + Bn)            // Bn int (per-t tickets, t<64)
#define WS_HS0  (WS_CNT + Bn)            // Bn*Hn u16
#define WS_HS1  (WS_HS0 + Bn * Hn / 2)
#define WS_HS2  (WS_HS1 + Bn * Hn / 2)
#define WS_PM   (WS_HS2 + Bn * Hn / 2)   // Bn*SPAD  [row][strip]
#define WS_PS   (WS_PM + Bn * SPAD)
#define WS_PBS  (WS_PS + Bn * SPAD)
#define WS_PBV  (WS_PBS + Bn * SPAD)     // int
#define WS_PBZ  (WS_PBV + Bn * SPAD)

// ---------------- threefry2x32 (Random123 / JAX schedule) ----------------
__device__ __forceinline__ void tf2x32(uint32_t k0, uint32_t k1,
                                       uint32_t x0, uint32_t x1,
                                       uint32_t& o0, uint32_t& o1) {
  uint32_t ks2 = k0 ^ k1 ^ 0x1BD11BDAu;
  x0 += k0; x1 += k1;
#define TFR(r) { x0 += x1; x1 = (x1 << r) | (x1 >> (32 - r)); x1 ^= x0; }
  TFR(13) TFR(15) TFR(26) TFR(6)  x0 += k1;  x1 += ks2 + 1u;
  TFR(17) TFR(29) TFR(16) TFR(24) x0 += ks2; x1 += k0 + 2u;
  TFR(13) TFR(15) TFR(26) TFR(6)  x0 += k0;  x1 += k1 + 3u;
  TFR(17) TFR(29) TFR(16) TFR(24) x0 += k1;  x1 += ks2 + 4u;
  TFR(13) TFR(15) TFR(26) TFR(6)  x0 += ks2; x1 += k0 + 5u;
#undef TFR
  o0 = x0; o1 = x1;
}

__device__ __forceinline__ uint32_t jax_bits32(uint32_t k0, uint32_t k1,
                                               uint32_t i, uint32_t total) {
#if JAX_PARTITIONABLE
  (void)total;
  uint32_t o0, o1; tf2x32(k0, k1, 0u, i, o0, o1); return o0 ^ o1;
#else
  uint32_t half = total >> 1;
  uint32_t o0, o1;
  if (i < half) { tf2x32(k0, k1, i, i + half, o0, o1); return o0; }
  tf2x32(k0, k1, i - half, i, o0, o1); return o1;
#endif
}

__device__ __forceinline__ void jax_splitkey(uint32_t k0, uint32_t k1,
                                             uint32_t idx, uint32_t num,
                                             uint32_t& s0, uint32_t& s1) {
#if JAX_PARTITIONABLE
  (void)num;
  tf2x32(k0, k1, 0u, idx, s0, s1);
#else
  uint32_t j0 = 2 * idx, j1 = 2 * idx + 1;
  uint32_t r0, r1;
  if (j0 < num) { tf2x32(k0, k1, j0, j0 + num, r0, r1); s0 = r0; }
  else          { tf2x32(k0, k1, j0 - num, j0, r0, r1); s0 = r1; }
  if (j1 < num) { tf2x32(k0, k1, j1, j1 + num, r0, r1); s1 = r0; }
  else          { tf2x32(k0, k1, j1 - num, j1, r0, r1); s1 = r1; }
#endif
}

__device__ __forceinline__ float bits_to_unit(uint32_t bits) {
  return __uint_as_float((bits >> 9) | 0x3F800000u) - 1.0f;
}

// ---------------- f32 -> 3x bf16 split (truncation; residual <= 2^-21) ----
struct Limbs3 { uint32_t p0, p1, p2; };

__device__ __forceinline__ Limbs3 split3_pair(float xa, float xb) {
  const uint32_t a0 = __float_as_uint(xa) & 0xFFFF0000u;
  const float ar1 = xa - __uint_as_float(a0);
  const uint32_t a1 = __float_as_uint(ar1) & 0xFFFF0000u;
  const float ar2 = ar1 - __uint_as_float(a1);
  const uint32_t a2 = __float_as_uint(ar2) & 0xFFFF0000u;
  const uint32_t b0 = __float_as_uint(xb) & 0xFFFF0000u;
  const float br1 = xb - __uint_as_float(b0);
  const uint32_t b1 = __float_as_uint(br1) & 0xFFFF0000u;
  const float br2 = br1 - __uint_as_float(b1);
  const uint32_t b2 = __float_as_uint(br2) & 0xFFFF0000u;
  Limbs3 r;
  r.p0 = (a0 >> 16) | b0;   // elem 2j low half, 2j+1 high half
  r.p1 = (a1 >> 16) | b1;
  r.p2 = (a2 >> 16) | b2;
  return r;
}

// ---------------- kernels ----------------

__global__ void init_k(float* h0, int* sampled, int* cnt) {
  int i = blockIdx.x * 256 + threadIdx.x;
  if (i < Bn * Hn) h0[i] = 0.0f;
  if (i < Bn) { sampled[i] = 0; cnt[i] = 0; }
}

// Fused GRU step. Grid: Hn/2 = 256 blocks x 256 threads.
// Block covers j = blk*2 + {0,1}, all 64 b. Waves: w = (q, kh):
//   q = j offset, kh = K-half. h stored transposed hT[k][b] (coalesced).
__global__ __launch_bounds__(256) void gru_fused(
    const float* __restrict__ emb,
    const float* __restrict__ w_ih, const float* __restrict__ b_ih,
    const float* __restrict__ w_hh, const float* __restrict__ b_hh,
    const float* __restrict__ hT_prev, float* __restrict__ hT_new,
    const int* __restrict__ sampled,
    u16* __restrict__ hs0, u16* __restrict__ hs1, u16* __restrict__ hs2) {
  const int tid = threadIdx.x;
  const int b = tid & 63;
  const int w = __builtin_amdgcn_readfirstlane(tid >> 6);  // wave 0..3
  const int q = w & 1;
  const int kh = w >> 1;
  const int j = blockIdx.x * 2 + q;

  __shared__ float Xs[En][64];   // x transposed, 64 KiB
  {
    const int g = tid >> 6;  // k-block of 64
    const float* src = emb + (size_t)sampled[b] * En + g * 64;
#pragma unroll
    for (int kk = 0; kk < 64; kk += 4) {
      float4 v = *(const float4*)(src + kk);
      Xs[g * 64 + kk + 0][b] = v.x;
      Xs[g * 64 + kk + 1][b] = v.y;
      Xs[g * 64 + kk + 2][b] = v.z;
      Xs[g * 64 + kk + 3][b] = v.w;
    }
  }
  __syncthreads();

  float a_r = 0.f, a_z = 0.f, a_n = 0.f;   // x-side partial dots
  float g_r = 0.f, g_z = 0.f, g_n = 0.f;   // h-side partial dots

  // phase X: K=En, this thread covers [kh*128, kh*128+128)
  {
    const float* wr = w_ih + (size_t)j * En;
    const float* wz = w_ih + (size_t)(Hn + j) * En;
    const float* wn = w_ih + (size_t)(2 * Hn + j) * En;
    const int kb = kh * 128;
#pragma unroll 8
    for (int k = kb; k < kb + 128; k++) {
      const float xv = Xs[k][b];
      a_r = fmaf(xv, wr[k], a_r);
      a_z = fmaf(xv, wz[k], a_z);
      a_n = fmaf(xv, wn[k], a_n);
    }
  }
  // phase H: K=Hn, thread covers [kh*256, +256); hT read coalesced from L2
  {
    const float* wr = w_hh + (size_t)j * Hn;
    const float* wz = w_hh + (size_t)(Hn + j) * Hn;
    const float* wn = w_hh + (size_t)(2 * Hn + j) * Hn;
    const int kb = kh * 256;
#pragma unroll 8
    for (int k = kb; k < kb + 256; k++) {
      const float hv = hT_prev[k * 64 + b];
      g_r = fmaf(hv, wr[k], g_r);
      g_z = fmaf(hv, wz[k], g_z);
      g_n = fmaf(hv, wn[k], g_n);
    }
  }

  __shared__ float red[6][2][64];
  if (kh == 1) {
    red[0][q][b] = a_r; red[1][q][b] = a_z; red[2][q][b] = a_n;
    red[3][q][b] = g_r; red[4][q][b] = g_z; red[5][q][b] = g_n;
  }
  __syncthreads();
  if (kh == 0) {
    a_r += red[0][q][b]; a_z += red[1][q][b]; a_n += red[2][q][b];
    g_r += red[3][q][b]; g_z += red[4][q][b]; g_n += red[5][q][b];
    const float gr = a_r + b_ih[j] + g_r + b_hh[j];
    const float gz = a_z + b_ih[Hn + j] + g_z + b_hh[Hn + j];
    const float r = 1.0f / (1.0f + expf(-gr));
    const float z = 1.0f / (1.0f + expf(-gz));
    const float ghn = g_n + b_hh[2 * Hn + j];
    const float n = tanhf(a_n + b_ih[2 * Hn + j] + r * ghn);
    const float hp = hT_prev[j * 64 + b];
    const float h = (1.0f - z) * n + z * hp;
    hT_new[j * 64 + b] = h;
    // 3-limb bf16 split for the logits MFMA A-operand (row-major [b][k])
    const uint32_t c0 = __float_as_uint(h) & 0xFFFF0000u;
    const float r1 = h - __uint_as_float(c0);
    const uint32_t c1 = __float_as_uint(r1) & 0xFFFF0000u;
    const float r2 = r1 - __uint_as_float(c1);
    const size_t ho = (size_t)b * Hn + j;
    hs0[ho] = (u16)(c0 >> 16);
    hs1[ho] = (u16)(c1 >> 16);
    hs2[ho] = (u16)(__float_as_uint(r2) >> 16);
  }
}

// Logits MFMA (split-bf16) + fused per-strip partials + in-kernel combine.
// Grid: NSTRIP=500 blocks x 256 thr (4 waves, 2x2 of 32x32), tile 64b x 64v.
__global__ __launch_bounds__(256, 2) void logits_mfma(
    const u16* __restrict__ hs0, const u16* __restrict__ hs1,
    const u16* __restrict__ hs2,
    const float* __restrict__ w_out, const float* __restrict__ b_out,
    float* __restrict__ out_dist,
    float* __restrict__ pM, float* __restrict__ pS, float* __restrict__ pBS,
    int* __restrict__ pBV, float* __restrict__ pBZ,
    int* __restrict__ cnt, float* __restrict__ rmA, float* __restrict__ rlA,
    int* __restrict__ sampled, float* __restrict__ out, int t) {
  const int tid = threadIdx.x;
  const int w = tid >> 6;
  const int lane = tid & 63;
  const int wm = (w >> 1) * 32;
  const int wn = (w & 1) * 32;
  const int lr = lane & 15;
  const int lg = lane >> 4;
  const int v0 = blockIdx.x * 64;

  __shared__ int s_dr[64];
  __shared__ float ldsM[64][2], ldsS[64][2], ldsBS[64][2], ldsBZ[64][2];
  __shared__ int ldsBV[64][2];
  __shared__ int s_tk;

  uint32_t kt0, kt1, kg0, kg1;
  jax_splitkey(0u, 1u, (uint32_t)t, (uint32_t)Tn, kt0, kt1);
  jax_splitkey(kt0, kt1, 1u, 2u, kg0, kg1);
  if (tid < 64) {
    uint32_t ke0, ke1;
    jax_splitkey(kt0, kt1, 0u, 2u, ke0, ke1);
    const uint32_t eb = jax_bits32(ke0, ke1, (uint32_t)tid, (uint32_t)Bn);
    s_dr[tid] = (0.1f >= bits_to_unit(eb)) ? 1 : 0;
  }
  __syncthreads();

  f32x4 acc[2][2] = {};

#pragma unroll 2
  for (int k0 = 0; k0 < Hn; k0 += 32) {
    bf16x8 a0[2], a1[2], a2[2];
#pragma unroll
    for (int mi = 0; mi < 2; mi++) {
      const size_t off = (size_t)(wm + mi * 16 + lr) * Hn + k0 + lg * 8;
      a0[mi] = *reinterpret_cast<const bf16x8*>(hs0 + off);
      a1[mi] = *reinterpret_cast<const bf16x8*>(hs1 + off);
      a2[mi] = *reinterpret_cast<const bf16x8*>(hs2 + off);
    }
    bf16x8 bb0[2], bb1[2], bb2[2];
#pragma unroll
    for (int ni = 0; ni < 2; ni++) {
      const float* src = w_out + (size_t)(v0 + wn + ni * 16 + lr) * Hn + k0 + lg * 8;
      const float4 x0 = *(const float4*)(src);
      const float4 x1 = *(const float4*)(src + 4);
      u32x4 q0, q1, q2;
      const Limbs3 l0 = split3_pair(x0.x, x0.y);
      const Limbs3 l1 = split3_pair(x0.z, x0.w);
      const Limbs3 l2 = split3_pair(x1.x, x1.y);
      const Limbs3 l3 = split3_pair(x1.z, x1.w);
      q0[0] = l0.p0; q1[0] = l0.p1; q2[0] = l0.p2;
      q0[1] = l1.p0; q1[1] = l1.p1; q2[1] = l1.p2;
      q0[2] = l2.p0; q1[2] = l2.p1; q2[2] = l2.p2;
      q0[3] = l3.p0; q1[3] = l3.p1; q2[3] = l3.p2;
      bb0[ni] = __builtin_bit_cast(bf16x8, q0);
      bb1[ni] = __builtin_bit_cast(bf16x8, q1);
      bb2[ni] = __builtin_bit_cast(bf16x8, q2);
    }
#pragma unroll
    for (int mi = 0; mi < 2; mi++)
#pragma unroll
      for (int ni = 0; ni < 2; ni++) {
        f32x4 c = acc[mi][ni];
        c = __builtin_amdgcn_mfma_f32_16x16x32_bf16(a0[mi], bb0[ni], c, 0, 0, 0);
        c = __builtin_amdgcn_mfma_f32_16x16x32_bf16(a0[mi], bb1[ni], c, 0, 0, 0);
        c = __builtin_amdgcn_mfma_f32_16x16x32_bf16(a1[mi], bb0[ni], c, 0, 0, 0);
        c = __builtin_amdgcn_mfma_f32_16x16x32_bf16(a1[mi], bb1[ni], c, 0, 0, 0);
        c = __builtin_amdgcn_mfma_f32_16x16x32_bf16(a0[mi], bb2[ni], c, 0, 0, 0);
        c = __builtin_amdgcn_mfma_f32_16x16x32_bf16(a2[mi], bb0[ni], c, 0, 0, 0);
        acc[mi][ni] = c;
      }
  }

  // bias + store raw z (normalized by norm_all_k at the end)
  float bias[2];
#pragma unroll
  for (int ni = 0; ni < 2; ni++) bias[ni] = b_out[v0 + wn + ni * 16 + lr];
#pragma unroll
  for (int mi = 0; mi < 2; mi++)
#pragma unroll
    for (int ni = 0; ni < 2; ni++)
#pragma unroll
      for (int r = 0; r < 4; r++) {
        acc[mi][ni][r] += bias[ni];
        const int brow = wm + mi * 16 + lg * 4 + r;
        out_dist[(size_t)(brow * Tn + t) * Vn + v0 + wn + ni * 16 + lr] =
            acc[mi][ni][r];
      }

  // per-(row, strip) partials: strip max, strip sumexp, Gumbel best (raw z)
  const float LU = -logf((float)Vn);
#pragma unroll
  for (int mi = 0; mi < 2; mi++) {
#pragma unroll
    for (int r = 0; r < 4; r++) {
      const int brow = wm + mi * 16 + lg * 4 + r;
      const int dr = s_dr[brow];
      const int vA = v0 + wn + lr, vB = vA + 16;
      const float zA = acc[mi][0][r], zB = acc[mi][1][r];
      float mz = fmaxf(zA, zB);
#pragma unroll
      for (int off = 1; off < 16; off <<= 1) mz = fmaxf(mz, __shfl_xor(mz, off, 64));
      float sz = expf(zA - mz) + expf(zB - mz);
#pragma unroll
      for (int off = 1; off < 16; off <<= 1) sz += __shfl_xor(sz, off, 64);
      const uint32_t bA = jax_bits32(kg0, kg1, (uint32_t)(brow * Vn + vA), 0u);
      const uint32_t bB = jax_bits32(kg0, kg1, (uint32_t)(brow * Vn + vB), 0u);
      const float uA = fmaxf(1e-9f, bits_to_unit(bA) + 1e-9f);
      const float uB = fmaxf(1e-9f, bits_to_unit(bB) + 1e-9f);
      const float glA = logf(-logf(uA));
      const float glB = logf(-logf(uB));
      const float sA = (dr ? LU : zA) - glA;
      const float sB = (dr ? LU : zB) - glB;
      float bs; int bv; float bz;
      if (sB > sA) { bs = sB; bv = vB; bz = zB; }
      else         { bs = sA; bv = vA; bz = zA; }
#pragma unroll
      for (int off = 1; off < 16; off <<= 1) {
        const float so = __shfl_xor(bs, off, 64);
        const int vo = __shfl_xor(bv, off, 64);
        const float zo = __shfl_xor(bz, off, 64);
        if (so > bs || (so == bs && vo < bv)) { bs = so; bv = vo; bz = zo; }
      }
      if (lr == 0) {
        ldsM[brow][w & 1] = mz; ldsS[brow][w & 1] = sz;
        ldsBS[brow][w & 1] = bs; ldsBV[brow][w & 1] = bv; ldsBZ[brow][w & 1] = bz;
      }
    }
  }
  __syncthreads();
  if (tid < 64) {
    const float m0 = ldsM[tid][0], m1 = ldsM[tid][1];
    const float mm = fmaxf(m0, m1);
    const float ss = ldsS[tid][0] * expf(m0 - mm) + ldsS[tid][1] * expf(m1 - mm);
    float bs = ldsBS[tid][0]; int bv = ldsBV[tid][0]; float bz = ldsBZ[tid][0];
    if (ldsBS[tid][1] > bs || (ldsBS[tid][1] == bs && ldsBV[tid][1] < bv)) {
      bs = ldsBS[tid][1]; bv = ldsBV[tid][1]; bz = ldsBZ[tid][1];
    }
    const int o = tid * SPAD + blockIdx.x;   // [row][strip]
    pM[o] = mm; pS[o] = ss; pBS[o] = bs; pBV[o] = bv; pBZ[o] = bz;
  }
  __syncthreads();

  // ---- ticket: last 8 blocks perform the cross-strip combine (8 rows each)
  if (tid == 0) {
    __threadfence();
    s_tk = __hip_atomic_fetch_add(&cnt[t], 1, __ATOMIC_ACQ_REL,
                                  __HIP_MEMORY_SCOPE_AGENT);
  }
  __syncthreads();
  const int ticket = s_tk;
  if (ticket >= NSTRIP - 8 && ticket < NSTRIP) {
    while (__hip_atomic_load(&cnt[t], __ATOMIC_ACQUIRE,
                             __HIP_MEMORY_SCOPE_AGENT) < NSTRIP) {
      __builtin_amdgcn_s_sleep(8);
    }
    const int base = (ticket - (NSTRIP - 8)) * 8;
    const int g = tid >> 5, l32 = tid & 31;
    const int row = base + g;
    float m = -INFINITY, ssum = 0.f;
    float bs = -INFINITY; int bv = Vn; float bz = 0.f;
    for (int s = l32; s < NSTRIP; s += 32) {
      const int o = row * SPAD + s;
      const float m2 = pM[o], s2 = pS[o];
      const float mn = fmaxf(m, m2);
      ssum = ssum * expf(m - mn) + s2 * expf(m2 - mn);
      m = mn;
      const float b2 = pBS[o]; const int v2 = pBV[o];
      if (b2 > bs || (b2 == bs && v2 < bv)) { bs = b2; bv = v2; bz = pBZ[o]; }
    }
#pragma unroll
    for (int off = 16; off >= 1; off >>= 1) {
      const float mo = __shfl_xor(m, off, 64);
      const float so = __shfl_xor(ssum, off, 64);
      const float mn = fmaxf(m, mo);
      ssum = ssum * expf(m - mn) + so * expf(mo - mn);
      m = mn;
      const float bo = __shfl_xor(bs, off, 64);
      const int vo = __shfl_xor(bv, off, 64);
      const float zo = __shfl_xor(bz, off, 64);
      if (bo > bs || (bo == bs && vo < bv)) { bs = bo; bv = vo; bz = zo; }
    }
    if (l32 == 0) {
      const float l = logf(ssum);
      rmA[t * Bn + row] = m;
      rlA[t * Bn + row] = l;
      sampled[row] = bv;
      out[OUT_SAMP + row * Tn + t] = (float)bv;
      const float d = (bz - m) - l;     // same op order as norm_all_k
      out[OUT_LOGP + row * Tn + t] = d;
      uint32_t ke0, ke1;
      jax_splitkey(kt0, kt1, 0u, 2u, ke0, ke1);
      const int dr =
          (0.1f >= bits_to_unit(jax_bits32(ke0, ke1, (uint32_t)row, (uint32_t)Bn)))
              ? 1 : 0;
      const float onp = fminf(fmaxf(expf(d), 1e-8f), 1.0f);
      const float offp = fminf(fmaxf(expf(dr ? LU : d), 1e-8f), 1.0f);
      out[OUT_CORR + row * Tn + t] = onp / offp;
    }
  }
}

// Final pass: normalize all dist in place, compute probs. Grid: Tn*250 blocks.
__global__ void norm_all_k(float* __restrict__ out_dist,
                           float* __restrict__ probs,
                           const float* __restrict__ rmA,
                           const float* __restrict__ rlA) {
  const int blk = blockIdx.x;
  const int t = blk / 250;
  const int c = blk % 250;
  const int tid = threadIdx.x;
  const int v = c * 128 + (tid & 127);
  const int half = tid >> 7;
  __shared__ float sm[64], sl[64];
  if (tid < 64) { sm[tid] = rmA[t * Bn + tid]; sl[tid] = rlA[t * Bn + tid]; }
  __syncthreads();
  float s = 0.f;
  for (int i = 0; i < 32; i++) {
    const int b = half * 32 + i;
    float* p = out_dist + (size_t)(b * Tn + t) * Vn + v;
    const float d = (*p - sm[b]) - sl[b];
    *p = d;
    s += expf(d);
  }
  __shared__ float red[256];
  red[tid] = s; __syncthreads();
  if (half == 0)
    probs[(size_t)t * Vn + v] = (red[tid] + red[tid + 128]) * 0.015625f;
}

// ---------------- host ----------------
extern "C" void kernel_launch(void* const* d_in, const int* in_sizes, int n_in,
                              void* d_out, int out_size, void* d_ws, size_t ws_size,
                              hipStream_t stream) {
  const float* emb   = (const float*)d_in[0];
  const float* w_ih  = (const float*)d_in[1];
  const float* b_ih  = (const float*)d_in[2];
  const float* w_hh  = (const float*)d_in[3];
  const float* b_hh  = (const float*)d_in[4];
  const float* w_out = (const float*)d_in[5];
  const float* b_out = (const float*)d_in[6];
  float* out = (float*)d_out;
  float* ws  = (float*)d_ws;

  float* hT[2] = { ws + WS_HT0, ws + WS_HT1 };
  float* rmA  = ws + WS_RM;
  float* rlA  = ws + WS_RL;
  int*   smp  = (int*)(ws + WS_SMP);
  int*   cnt  = (int*)(ws + WS_CNT);
  u16*   hs0  = (u16*)(ws + WS_HS0);
  u16*   hs1  = (u16*)(ws + WS_HS1);
  u16*   hs2  = (u16*)(ws + WS_HS2);
  float* pM   = ws + WS_PM;
  float* pS   = ws + WS_PS;
  float* pBS  = ws + WS_PBS;
  int*   pBV  = (int*)(ws + WS_PBV);
  float* pBZ  = ws + WS_PBZ;

  init_k<<<(Bn * Hn + 255) / 256, 256, 0, stream>>>(hT[0], smp, cnt);

  for (int t = 0; t < Tn; t++) {
    float* hp = hT[t & 1];
    float* hn = hT[(t + 1) & 1];
    gru_fused<<<Hn / 2, 256, 0, stream>>>(emb, w_ih, b_ih, w_hh, b_hh,
                                          hp, hn, smp, hs0, hs1, hs2);
    logits_mfma<<<NSTRIP, 256, 0, stream>>>(hs0, hs1, hs2, w_out, b_out,
                                            out + OUT_DIST, pM, pS, pBS, pBV, pBZ,
                                            cnt, rmA, rlA, smp, out, t);
  }
  norm_all_k<<<Tn * 250, 256, 0, stream>>>(out + OUT_DIST, out + OUT_PROB,
                                           rmA, rlA);
}